// Round 8
// baseline (223.332 us; speedup 1.0000x reference)
//
#include <hip/hip_runtime.h>

// RoIAlign: features (2,256,200,304) fp32 NCHW, rois (512,5) fp32,
// out (512,256,7,7) fp32. OUT=7x7, sampling ratio G=2, scale 0.25.
//
// Round 8: (1) transpose tile widened to 64ch x 128px: phase-1 wave-inst
// reads 2 channel-rows x 512 B contiguous (vs 4 x 256 B) -> larger stream
// granularity toward the 6.5 TB/s sequential ceiling. LDS 33 KB, pitch 129
// (phase-2 reads stay 2-way/free; phase-1 scalar writes 4-way, hidden).
// (2) gather: 64-thread blocks, 4 channels/lane via uint2 -> one 512 B
// wave-inst per corner (halved load-instruction count).

#define OUT_H 7
#define OUT_W 7
constexpr float SPATIAL_SCALE = 0.25f;
constexpr int CN = 256;   // channels
constexpr int FH = 200;
constexpr int FW = 304;
constexpr int N_IMG = 2;
constexpr int N_ROIS = 512;
constexpr int PIX = FH * FW;               // 60800 = 475 * 128
constexpr size_t PLANE = (size_t)PIX;
constexpr size_t NHWC_ELEMS = (size_t)N_IMG * PLANE * CN;
constexpr size_t NHWC_BF16_BYTES = NHWC_ELEMS * sizeof(unsigned short);

constexpr int CT = 64;    // channel tile
constexpr int PT = 128;   // pixel tile
constexpr int TP = PT + 1; // LDS pitch 129

__device__ __forceinline__ unsigned short f2bf_rne(float f) {
    unsigned int u = __float_as_uint(f);
    unsigned int r = (u + 0x7FFFu + ((u >> 16) & 1u)) >> 16;  // RNE
    return (unsigned short)r;
}

// ---------------- tiled transpose NCHW fp32 -> NHWC bf16 ----------------
// grid (PIX/PT = 475, N_IMG*CN/CT = 8), 256 threads.
// Phase 1: thread (q = t&31, rr = t>>5) loads float4 of channel c = rr+8i
//   at pixel 4q -> per wave-inst 2 channel rows x 512 B contiguous.
//   LDS write bank = (c + 4q + j) % 32 -> 4-way (1.58x, hidden).
// Phase 2: thread (cq = t&15, p0 = t>>4) packs channels 4cq..4cq+3 of pixel
//   p = p0 + 16*i2 -> uint2; per 16-lane cluster one pixel's 64 ch = 128 B
//   contiguous (2 full lines). LDS read bank = (4cq+i+p0+16i2)%32:
//   4cq+p0 covers 0..63 once -> 2 lanes/bank -> free.
__global__ __launch_bounds__(256) void nchw_to_nhwc_bf16_tiled(
    const float* __restrict__ in, unsigned short* __restrict__ ws)
{
    const int pbase = blockIdx.x * PT;
    const int nc = blockIdx.y;           // 0..7
    const int n = nc >> 2;
    const int cbase = (nc & 3) * CT;

    __shared__ float tile[CT][TP];

    {
        const int q  = threadIdx.x & 31; // float4 slot: pixels 4q..4q+3
        const int rr = threadIdx.x >> 5; // 0..7
        const float* src = in + ((size_t)n * CN + cbase) * PLANE + pbase + 4 * q;
#pragma unroll
        for (int i = 0; i < 8; ++i) {
            const int c = rr + 8 * i;
            const float4 v = *(const float4*)(src + (size_t)c * PLANE);
            tile[c][4 * q + 0] = v.x;
            tile[c][4 * q + 1] = v.y;
            tile[c][4 * q + 2] = v.z;
            tile[c][4 * q + 3] = v.w;
        }
    }
    __syncthreads();
    {
        const int cq = threadIdx.x & 15; // channel quad: channels 4cq..4cq+3
        const int p0 = threadIdx.x >> 4; // 0..15
        unsigned short* dstbase =
            ws + ((size_t)n * PLANE + pbase) * CN + cbase + 4 * cq;
#pragma unroll
        for (int i2 = 0; i2 < 8; ++i2) {
            const int p = p0 + 16 * i2;
            const float f0 = tile[4 * cq + 0][p];
            const float f1 = tile[4 * cq + 1][p];
            const float f2 = tile[4 * cq + 2][p];
            const float f3 = tile[4 * cq + 3][p];
            uint2 pk;
            pk.x = (unsigned int)f2bf_rne(f0) | ((unsigned int)f2bf_rne(f1) << 16);
            pk.y = (unsigned int)f2bf_rne(f2) | ((unsigned int)f2bf_rne(f3) << 16);
            *(uint2*)(dstbase + (size_t)p * CN) = pk;
        }
    }
}

// ---------------- gather on NHWC bf16: (roi, ph) blocks, XCD-swizzled ----
// 64 threads = 1 wave; lane t handles channels 4t..4t+3 (uint2 loads).
// One corner load = 64 lanes x 8 B = 512 B contiguous per instruction.
// 1-D grid of 3584; decode so all 7 ph of a roi share (id % 8) => same XCD.
__global__ __launch_bounds__(64) void roi_align_nhwc_bf16(
    const unsigned short* __restrict__ ws,
    const float* __restrict__ rois,
    float* __restrict__ out)
{
    const int b = blockIdx.x;
    const int x = b & 7;                 // XCD residue
    const int s_id = b >> 3;             // 0..447
    const int r  = (s_id / 7) * 8 + x;   // roi
    const int ph = s_id % 7;             // output row
    const int t  = threadIdx.x;          // channels 4t..4t+3

    __shared__ float s_roi[5];
    __shared__ int   s_off[28][4];
    __shared__ float s_w[28][4];
    __shared__ int   s_b;

    if (t < 5) s_roi[t] = rois[r * 5 + t];
    __syncthreads();

    if (t < 28) {
        const int s  = t;
        const int gy = s / 14;
        const int ix = s % 14;
        const float x1 = s_roi[1] * SPATIAL_SCALE - 0.5f;
        const float y1 = s_roi[2] * SPATIAL_SCALE - 0.5f;
        const float x2 = s_roi[3] * SPATIAL_SCALE - 0.5f;
        const float y2 = s_roi[4] * SPATIAL_SCALE - 0.5f;
        const float bin_w = (x2 - x1) / OUT_W;
        const float bin_h = (y2 - y1) / OUT_H;
        const float y = y1 + ph * bin_h + (gy + 0.5f) * bin_h * 0.5f;
        const float xf = x1 + (ix >> 1) * bin_w + ((ix & 1) + 0.5f) * bin_w * 0.5f;
        const float validf =
            (y > -1.0f && y < (float)FH && xf > -1.0f && xf < (float)FW) ? 1.0f : 0.0f;
        const float yc = fminf(fmaxf(y, 0.0f), (float)(FH - 1));
        const float xc = fminf(fmaxf(xf, 0.0f), (float)(FW - 1));
        const int y0 = (int)floorf(yc);
        const int x0 = (int)floorf(xc);
        const int y1i = min(y0 + 1, FH - 1);
        const int x1i = min(x0 + 1, FW - 1);
        const float ly = yc - (float)y0;
        const float lx = xc - (float)x0;
        const float hy = 1.0f - ly;
        const float hx = 1.0f - lx;
        s_off[s][0] = (y0  * FW + x0 ) * CN;
        s_off[s][1] = (y0  * FW + x1i) * CN;
        s_off[s][2] = (y1i * FW + x0 ) * CN;
        s_off[s][3] = (y1i * FW + x1i) * CN;
        s_w[s][0] = hy * hx * validf;
        s_w[s][1] = hy * lx * validf;
        s_w[s][2] = ly * hx * validf;
        s_w[s][3] = ly * lx * validf;
    }
    if (t == 0) s_b = (int)s_roi[0];
    __syncthreads();

    const unsigned short* base = ws + (size_t)s_b * (PLANE * CN) + 4 * t;

    float acc0[OUT_W] = {0.f, 0.f, 0.f, 0.f, 0.f, 0.f, 0.f};
    float acc1[OUT_W] = {0.f, 0.f, 0.f, 0.f, 0.f, 0.f, 0.f};
    float acc2[OUT_W] = {0.f, 0.f, 0.f, 0.f, 0.f, 0.f, 0.f};
    float acc3[OUT_W] = {0.f, 0.f, 0.f, 0.f, 0.f, 0.f, 0.f};
#pragma unroll
    for (int s = 0; s < 28; ++s) {
        const int pw = (s % 14) >> 1;
#pragma unroll
        for (int k = 0; k < 4; ++k) {
            const uint2 u = *(const uint2*)(base + s_off[s][k]);
            const float f0 = __uint_as_float(u.x << 16);
            const float f1 = __uint_as_float(u.x & 0xFFFF0000u);
            const float f2 = __uint_as_float(u.y << 16);
            const float f3 = __uint_as_float(u.y & 0xFFFF0000u);
            const float w = s_w[s][k];
            acc0[pw] = fmaf(w, f0, acc0[pw]);
            acc1[pw] = fmaf(w, f1, acc1[pw]);
            acc2[pw] = fmaf(w, f2, acc2[pw]);
            acc3[pw] = fmaf(w, f3, acc3[pw]);
        }
    }

    const size_t outbase = ((size_t)r * CN + 4 * t) * (OUT_H * OUT_W) + (size_t)ph * OUT_W;
#pragma unroll
    for (int pw = 0; pw < OUT_W; ++pw) {
        out[outbase + 0 * (OUT_H * OUT_W) + pw] = acc0[pw] * 0.25f;
        out[outbase + 1 * (OUT_H * OUT_W) + pw] = acc1[pw] * 0.25f;
        out[outbase + 2 * (OUT_H * OUT_W) + pw] = acc2[pw] * 0.25f;
        out[outbase + 3 * (OUT_H * OUT_W) + pw] = acc3[pw] * 0.25f;
    }
}

// ---------------- fallback: NCHW gather (round-1 kernel) ----------------
__global__ __launch_bounds__(256) void roi_align_nchw(
    const float* __restrict__ feat,
    const float* __restrict__ rois,
    float* __restrict__ out)
{
    const int r  = blockIdx.x;
    const int ph = blockIdx.y;
    const int c  = threadIdx.x;

    __shared__ float s_roi[5];
    __shared__ int   s_off[28][4];
    __shared__ float s_w[28][4];
    __shared__ int   s_b;

    if (threadIdx.x < 5) s_roi[threadIdx.x] = rois[r * 5 + threadIdx.x];
    __syncthreads();

    if (threadIdx.x < 28) {
        const int s  = threadIdx.x;
        const int gy = s / 14;
        const int ix = s % 14;
        const float x1 = s_roi[1] * SPATIAL_SCALE - 0.5f;
        const float y1 = s_roi[2] * SPATIAL_SCALE - 0.5f;
        const float x2 = s_roi[3] * SPATIAL_SCALE - 0.5f;
        const float y2 = s_roi[4] * SPATIAL_SCALE - 0.5f;
        const float bin_w = (x2 - x1) / OUT_W;
        const float bin_h = (y2 - y1) / OUT_H;
        const float y = y1 + ph * bin_h + (gy + 0.5f) * bin_h * 0.5f;
        const float xf = x1 + (ix >> 1) * bin_w + ((ix & 1) + 0.5f) * bin_w * 0.5f;
        const float validf =
            (y > -1.0f && y < (float)FH && xf > -1.0f && xf < (float)FW) ? 1.0f : 0.0f;
        const float yc = fminf(fmaxf(y, 0.0f), (float)(FH - 1));
        const float xc = fminf(fmaxf(xf, 0.0f), (float)(FW - 1));
        const int y0 = (int)floorf(yc);
        const int x0 = (int)floorf(xc);
        const int y1i = min(y0 + 1, FH - 1);
        const int x1i = min(x0 + 1, FW - 1);
        const float ly = yc - (float)y0;
        const float lx = xc - (float)x0;
        const float hy = 1.0f - ly;
        const float hx = 1.0f - lx;
        s_off[s][0] = y0  * FW + x0;
        s_off[s][1] = y0  * FW + x1i;
        s_off[s][2] = y1i * FW + x0;
        s_off[s][3] = y1i * FW + x1i;
        s_w[s][0] = hy * hx * validf;
        s_w[s][1] = hy * lx * validf;
        s_w[s][2] = ly * hx * validf;
        s_w[s][3] = ly * lx * validf;
    }
    if (threadIdx.x == 0) s_b = (int)s_roi[0];
    __syncthreads();

    const float* base = feat + ((size_t)s_b * CN + c) * PLANE;

    float acc[OUT_W] = {0.f, 0.f, 0.f, 0.f, 0.f, 0.f, 0.f};
#pragma unroll
    for (int s = 0; s < 28; ++s) {
        const float v0 = base[s_off[s][0]];
        const float v1 = base[s_off[s][1]];
        const float v2 = base[s_off[s][2]];
        const float v3 = base[s_off[s][3]];
        acc[(s % 14) >> 1] += s_w[s][0] * v0 + s_w[s][1] * v1 +
                              s_w[s][2] * v2 + s_w[s][3] * v3;
    }

    const size_t outbase = ((size_t)r * CN + c) * (OUT_H * OUT_W) + (size_t)ph * OUT_W;
#pragma unroll
    for (int pw = 0; pw < OUT_W; ++pw) {
        out[outbase + pw] = acc[pw] * 0.25f;
    }
}

extern "C" void kernel_launch(void* const* d_in, const int* in_sizes, int n_in,
                              void* d_out, int out_size, void* d_ws, size_t ws_size,
                              hipStream_t stream) {
    const float* feat = (const float*)d_in[0];
    const float* rois = (const float*)d_in[1];
    float* out = (float*)d_out;

    if (ws_size >= NHWC_BF16_BYTES) {
        unsigned short* ws = (unsigned short*)d_ws;
        dim3 tgrid(PIX / PT, (N_IMG * CN) / CT, 1);  // 475 x 8 = 3800 blocks
        nchw_to_nhwc_bf16_tiled<<<tgrid, dim3(256, 1, 1), 0, stream>>>(feat, ws);
        roi_align_nhwc_bf16<<<dim3(N_ROIS * OUT_H, 1, 1), dim3(64, 1, 1), 0, stream>>>(
            ws, rois, out);
    } else {
        dim3 grid(N_ROIS, OUT_H, 1);
        roi_align_nchw<<<grid, dim3(256, 1, 1), 0, stream>>>(feat, rois, out);
    }
}